// Round 1
// 498.519 us; speedup vs baseline: 1.0657x; 1.0657x over previous
//
#include <hip/hip_runtime.h>
#include <hip/hip_fp16.h>
#include <math.h>

#define NN 100000
#define IN_DIM 256
#define HCH 128      // HEADS*HID
#define OUT_DIM 64
#define EE 1600000
#define NEG_SLOPE 0.2f

#define NB 1024      // dst buckets
#define NPB 98       // nodes per bucket (1024*98 >= 100000)
#define CAP 2048     // bucket capacity (mean 1562, std ~40 -> 12 sigma margin)

typedef _Float16 half8v __attribute__((ext_vector_type(8)));
typedef _Float16 half4v __attribute__((ext_vector_type(4)));
typedef _Float16 half2v __attribute__((ext_vector_type(2)));
typedef float float4v __attribute__((ext_vector_type(4)));

__device__ __forceinline__ float lrelu(float v) { return v > 0.f ? v : NEG_SLOPE * v; }

// ---- convert: wt[l][col][k] = W_l[k][col] fp16 ; fcw16[l][col][k] = fcW[l*128+k][col]
__global__ void convw_kernel(const float* __restrict__ W0, const float* __restrict__ W1,
                             const float* __restrict__ fcW,
                             _Float16* __restrict__ wt, _Float16* __restrict__ fcw16)
{
    int i = blockIdx.x * 256 + threadIdx.x;
    if (i < 2 * IN_DIM * HCH) {
        int l = i >> 15, rem = i & 32767;
        int c = rem >> 8, k = rem & 255;
        const float* W = l ? W1 : W0;
        wt[i] = (_Float16)W[(size_t)k * HCH + c];
        return;
    }
    int j = i - 2 * IN_DIM * HCH;
    if (j < 2 * HCH * OUT_DIM) {
        int l = j >> 13, rem = j & 8191;
        int c = rem >> 7, k = rem & 127;
        fcw16[j] = (_Float16)fcW[(size_t)(l * HCH + k) * OUT_DIM + c];
    }
}

// ---------------- fused GEMM (fp16 MFMA), BOTH layers in one pass ----------
// 64-row tiles, 1563 blocks; 4 waves as 2x2, wave tile 32x128 (2x8 frags)
// x is read ONCE for both layers (saves ~100MB HBM vs two passes).
__global__ __launch_bounds__(256, 3) void gemm_mfma(
    const float* __restrict__ x, const _Float16* __restrict__ wt,
    const float* __restrict__ attS0, const float* __restrict__ attD0,
    const float* __restrict__ attS1, const float* __restrict__ attD1,
    _Float16* __restrict__ h16, float* __restrict__ a_s, float* __restrict__ a_d, int n)
{
    __shared__ _Float16 smem[64 * 72 + 256 * 72];   // A[64][72] then B[256][72] = 46.1KB
    __shared__ float attv[4][128];                   // [layer*2+kind][col]
    _Float16 (*As)[72] = (_Float16(*)[72])smem;
    _Float16 (*Bs)[72] = (_Float16(*)[72])(smem + 64 * 72);
    const int tid = threadIdx.x;
    const int lane = tid & 63, wave = tid >> 6;
    const int wm = wave & 1, wn = wave >> 1;
    const int q = lane >> 4, r16 = lane & 15;
    const int row0 = blockIdx.x * 64;

    if (tid < 128) {
        attv[0][tid] = attS0[tid]; attv[1][tid] = attD0[tid];
        attv[2][tid] = attS1[tid]; attv[3][tid] = attD1[tid];
    }

    float4v acc[2][8];
#pragma unroll
    for (int i = 0; i < 2; ++i)
#pragma unroll
        for (int j = 0; j < 8; ++j) acc[i][j] = (float4v){0.f, 0.f, 0.f, 0.f};

    const int ar = tid >> 2, aq = tid & 3;   // A: row, k-quarter (16 floats)
    const bool rok = (row0 + ar) < n;
    for (int kt = 0; kt < IN_DIM; kt += 64) {
        const float* xp = x + (size_t)(row0 + ar) * IN_DIM + kt + aq * 16;
#pragma unroll
        for (int i = 0; i < 4; ++i) {
            float4 v = rok ? *(const float4*)(xp + i * 4) : make_float4(0.f, 0.f, 0.f, 0.f);
            half4v hv = { (_Float16)v.x, (_Float16)v.y, (_Float16)v.z, (_Float16)v.w };
            *(half4v*)&As[ar][aq * 16 + i * 4] = hv;
        }
        // B: one gcol (layer*128+c) per thread, 64 k-halves
        const _Float16* wp = wt + (size_t)tid * IN_DIM + kt;
#pragma unroll
        for (int i = 0; i < 8; ++i)
            *(half8v*)&Bs[tid][i * 8] = *(const half8v*)(wp + i * 8);
        __syncthreads();
#pragma unroll
        for (int s = 0; s < 2; ++s) {
            half8v af[2], bf[8];
#pragma unroll
            for (int t = 0; t < 2; ++t)
                af[t] = *(half8v*)&As[wm * 32 + t * 16 + r16][s * 32 + q * 8];
#pragma unroll
            for (int t = 0; t < 8; ++t)
                bf[t] = *(half8v*)&Bs[wn * 128 + t * 16 + r16][s * 32 + q * 8];
#pragma unroll
            for (int mt = 0; mt < 2; ++mt)
#pragma unroll
                for (int nt = 0; nt < 8; ++nt)
                    acc[mt][nt] = __builtin_amdgcn_mfma_f32_16x16x32_f16(
                        af[mt], bf[nt], acc[mt][nt], 0, 0, 0);
        }
        __syncthreads();
    }
    // epilogue: repack C to fp16 via LDS (C layout: row=q*4+reg, col=r16)
    _Float16 (*eb)[264] = (_Float16(*)[264])smem;   // 64x264x2 = 33.8 KB fits in smem
#pragma unroll
    for (int mt = 0; mt < 2; ++mt) {
        const int er = wm * 32 + mt * 16 + q * 4;
#pragma unroll
        for (int reg = 0; reg < 4; ++reg)
#pragma unroll
            for (int nt = 0; nt < 8; ++nt)
                eb[er + reg][wn * 128 + nt * 16 + r16] = (_Float16)acc[mt][nt][reg];
    }
    __syncthreads();
    // write h16 (per-layer arrays) + attention scores for both layers
    const int r = tid >> 2, qq = tid & 3;    // qq: 64-col quarter -> (layer, head)
    const int grow = row0 + r;
    if (grow < n) {
        const int l2 = qq >> 1;              // layer
        const int hh = qq & 1;               // head
        const float* avS = &attv[l2 * 2 + 0][hh * 64];
        const float* avD = &attv[l2 * 2 + 1][hh * 64];
        _Float16* hout = h16 + (size_t)l2 * NN * HCH + (size_t)grow * HCH + hh * 64;
        float ds = 0.f, dd = 0.f;
#pragma unroll
        for (int i = 0; i < 8; ++i) {
            half8v v = *(half8v*)&eb[r][qq * 64 + i * 8];
            *(half8v*)(hout + i * 8) = v;
#pragma unroll
            for (int j = 0; j < 8; ++j) {
                float f = (float)v[j];
                ds = fmaf(f, avS[i * 8 + j], ds);
                dd = fmaf(f, avD[i * 8 + j], dd);
            }
        }
        a_s[(size_t)l2 * 2 * NN + 2 * grow + hh] = ds;
        a_d[(size_t)l2 * 2 * NN + 2 * grow + hh] = dd;
    }
}

// ---------------- bucket edges by dst region (1024 thr for TLP) -------------
__global__ __launch_bounds__(1024) void bucket_kernel(const int* __restrict__ src,
                                                      const int* __restrict__ dst,
                                                      int* __restrict__ gcursor,
                                                      int* __restrict__ bstore, int e)
{
    __shared__ int hist[NB];
    __shared__ int base[NB];
    const int tid = threadIdx.x;
    const int per = (e + gridDim.x - 1) / gridDim.x;
    const int e0 = blockIdx.x * per;
    const int e1 = min(e, e0 + per);
    for (int i = tid; i < NB; i += 1024) hist[i] = 0;
    __syncthreads();
    for (int i = e0 + tid; i < e1; i += 1024)
        atomicAdd(&hist[dst[i] / NPB], 1);
    __syncthreads();
    for (int b = tid; b < NB; b += 1024) {
        int c = hist[b];
        base[b] = c ? atomicAdd(&gcursor[b], c) : 0;
        hist[b] = 0;
    }
    __syncthreads();
    for (int i = e0 + tid; i < e1; i += 1024) {
        int d = dst[i];
        int s = src[i];
        int b = d / NPB;
        int pos = base[b] + atomicAdd(&hist[b], 1);
        if (pos >= 0 && pos < CAP) bstore[b * CAP + pos] = (s << 7) | (d - b * NPB);
    }
}

// ---------------- per-bucket LDS counting sort (in place) -------------------
__global__ __launch_bounds__(256) void sort_kernel(
    const int* __restrict__ gcursor, int* __restrict__ bstore,
    int* __restrict__ gstart, int* __restrict__ gend, int n)
{
    __shared__ int raw[CAP];
    __shared__ int sorted[CAP];
    __shared__ int curs[128];
    __shared__ int scanbuf[128];
    const int tid = threadIdx.x;
    const int b = blockIdx.x;
    const int node0 = b * NPB;
    const int nnode = min(NPB, n - node0);
    if (nnode <= 0) return;
    int cnt = gcursor[b];
    cnt = cnt < 0 ? 0 : (cnt > CAP ? CAP : cnt);

    for (int i = tid; i < cnt; i += 256) raw[i] = bstore[b * CAP + i];
    if (tid < 128) curs[tid] = 0;
    __syncthreads();
    for (int i = tid; i < cnt; i += 256) atomicAdd(&curs[raw[i] & 127], 1);
    __syncthreads();
    if (tid < 128) scanbuf[tid] = curs[tid];
    __syncthreads();
    for (int off = 1; off < 128; off <<= 1) {
        int v = 0;
        if (tid < 128) { v = scanbuf[tid]; if (tid >= off) v += scanbuf[tid - off]; }
        __syncthreads();
        if (tid < 128) scanbuf[tid] = v;
        __syncthreads();
    }
    if (tid < 128) {
        int ex = tid ? scanbuf[tid - 1] : 0;
        curs[tid] = ex;
        if (tid < nnode) {
            gstart[node0 + tid] = b * CAP + ex;
            gend[node0 + tid] = b * CAP + scanbuf[tid];
        }
    }
    __syncthreads();
    for (int i = tid; i < cnt; i += 256) {
        int item = raw[i];
        int pos = atomicAdd(&curs[item & 127], 1);
        if (pos >= 0 && pos < CAP) sorted[pos] = item >> 7;
    }
    __syncthreads();
    for (int i = tid; i < cnt; i += 256) bstore[b * CAP + i] = sorted[i];
}

// ---------------- per-node softmax aggregation (fp16 gather) ----------------
// 6250 blocks; each wave serially handles 4 consecutive nodes.
// NEW: 4 edges in flight per wave; 16 lanes x half8 (16B) cover one 256B row.
//   lane = w*16 + cl : w = edge sub-slot (0..3), cl = column group (8 cols).
//   Edge count padded to multiple of 4; padded slots have p=0/src=0 (exact 0).
__global__ __launch_bounds__(256) void agg_kernel(
    const _Float16* __restrict__ h16, const float2* __restrict__ a_s,
    const float2* __restrict__ a_d, const int* __restrict__ gstart,
    const int* __restrict__ gend, const int* __restrict__ ssort,
    const float* __restrict__ bias, _Float16* __restrict__ xc16, int n)
{
    __shared__ float2 sh[4][2][64];   // [wave][head][slot]: (src_bits, p)
    const int wid = threadIdx.x >> 6, lane = threadIdx.x & 63;
    const int wbase = (blockIdx.x * 4 + wid) * 4;
    const int cl = lane & 15;         // column group: cols 8*cl .. 8*cl+7
    const int w  = lane >> 4;         // edge sub-slot 0..3
    const int hh = cl >> 3;           // head for these columns
    const float2* myh = &sh[wid][hh][0];

    float bv[8];
#pragma unroll
    for (int j = 0; j < 8; ++j) bv[j] = bias[cl * 8 + j];

    for (int ni = 0; ni < 4; ++ni) {
        const int node = wbase + ni;
        const bool valid = node < n;
        const int nn = valid ? node : 0;
        int start = gstart[nn], end = gend[nn];
        start = start < 0 ? 0 : (start > NB * CAP ? NB * CAP : start);
        end = end < start ? start : (end > NB * CAP ? NB * CAP : end);
        const float2 ad = a_d[nn];
        const float2 asn = a_s[nn];

        float acc[8] = {0.f, 0.f, 0.f, 0.f, 0.f, 0.f, 0.f, 0.f};
        float s0 = 0.f, s1 = 0.f;

        for (int base = start; base < end; base += 64) {
            const int j = base + lane;
            const int cnt = min(64, end - base);
            float p0 = 0.f, p1 = 0.f;
            int s = 0;
            if (j < end) {
                s = ssort[j];
                if ((unsigned)s >= (unsigned)n) s = 0;   // poison guard
                float2 a = a_s[s];
                p0 = __expf(lrelu(a.x + ad.x));
                p1 = __expf(lrelu(a.y + ad.y));
            }
            s0 += p0;
            s1 += p1;
            sh[wid][0][lane] = make_float2(__int_as_float(s), p0);
            sh[wid][1][lane] = make_float2(__int_as_float(s), p1);
            __builtin_amdgcn_wave_barrier();
            const int cnt4 = (cnt + 3) & ~3;
            for (int t = 0; t < cnt4; t += 4) {
                const float2 e = myh[t + w];
                const half8v hv = *(const half8v*)(
                    h16 + (size_t)__float_as_int(e.x) * HCH + cl * 8);
#pragma unroll
                for (int j2 = 0; j2 < 8; ++j2)
                    acc[j2] = fmaf(e.y, (float)hv[j2], acc[j2]);
            }
            __builtin_amdgcn_wave_barrier();
        }
        // self loop (sub-slot 0 only, so it is counted once after the reduce)
        const float ps0 = __expf(lrelu(asn.x + ad.x));
        const float ps1 = __expf(lrelu(asn.y + ad.y));
        if (w == 0) {
            const half8v hv = *(const half8v*)(h16 + (size_t)nn * HCH + cl * 8);
            const float pl = hh ? ps1 : ps0;
#pragma unroll
            for (int j2 = 0; j2 < 8; ++j2)
                acc[j2] = fmaf(pl, (float)hv[j2], acc[j2]);
        }
        if (lane == 0) { s0 += ps0; s1 += ps1; }
        // combine the 4 edge sub-slots
#pragma unroll
        for (int j2 = 0; j2 < 8; ++j2) {
            acc[j2] += __shfl_xor(acc[j2], 16, 64);
            acc[j2] += __shfl_xor(acc[j2], 32, 64);
        }
        // softmax denominators over all staged slots
#pragma unroll
        for (int m = 32; m >= 1; m >>= 1) {
            s0 += __shfl_xor(s0, m, 64);
            s1 += __shfl_xor(s1, m, 64);
        }
        if (valid && lane < 16) {
            const float inv = 1.f / (hh ? s1 : s0);
            half8v o;
#pragma unroll
            for (int j2 = 0; j2 < 8; ++j2)
                o[j2] = (_Float16)fmaxf(acc[j2] * inv + bv[j2], 0.f);
            *(half8v*)(xc16 + (size_t)node * HCH + cl * 8) = o;
        }
    }
}

// ---------------- FC half via MFMA: out (+)= xc16 @ fcW_half + fcb ----------
// 64-row tiles, wave w handles rows w*16..w*16+15; B direct from global (L1-hot)
__global__ __launch_bounds__(256) void fc_mfma(const _Float16* __restrict__ xc16,
                                               const _Float16* __restrict__ fw16,
                                               const float* __restrict__ fcb,
                                               float* __restrict__ out, int n, int beta)
{
    __shared__ _Float16 axs[64][136];
    const int tid = threadIdx.x;
    const int lane = tid & 63, wave = tid >> 6;
    const int q = lane >> 4, r16 = lane & 15;
    const int row0 = blockIdx.x * 64;

    // stage A: 64 rows x 128 k (4 half8 loads/thread, coalesced)
#pragma unroll
    for (int i = 0; i < 4; ++i) {
        const int idx = i * 256 + tid;
        const int row = idx >> 4;
        const int kg = (idx & 15) * 8;
        half8v v = { 0, 0, 0, 0, 0, 0, 0, 0 };
        if (row0 + row < n)
            v = *(const half8v*)(xc16 + (size_t)(row0 + row) * HCH + kg);
        *(half8v*)&axs[row][kg] = v;
    }
    __syncthreads();

    float4v acc[4];
#pragma unroll
    for (int i = 0; i < 4; ++i) acc[i] = (float4v){0.f, 0.f, 0.f, 0.f};
#pragma unroll
    for (int s = 0; s < 4; ++s) {
        const half8v af = *(half8v*)&axs[wave * 16 + r16][s * 32 + q * 8];
#pragma unroll
        for (int nt = 0; nt < 4; ++nt) {
            const half8v bf =
                *(const half8v*)(fw16 + (size_t)(nt * 16 + r16) * HCH + s * 32 + q * 8);
            acc[nt] = __builtin_amdgcn_mfma_f32_16x16x32_f16(af, bf, acc[nt], 0, 0, 0);
        }
    }
#pragma unroll
    for (int nt = 0; nt < 4; ++nt) {
        const int col = nt * 16 + r16;
#pragma unroll
        for (int reg = 0; reg < 4; ++reg) {
            const int row = row0 + wave * 16 + q * 4 + reg;
            if (row < n) {
                float v = acc[nt][reg];
                if (beta) v += out[(size_t)row * OUT_DIM + col];
                else v += fcb[col];
                out[(size_t)row * OUT_DIM + col] = v;
            }
        }
    }
}

// ---------------- launch ----------------
extern "C" void kernel_launch(void* const* d_in, const int* in_sizes, int n_in,
                              void* d_out, int out_size, void* d_ws, size_t ws_size,
                              hipStream_t stream)
{
    const float* x = (const float*)d_in[0];
    const int* ei[2] = { (const int*)d_in[1], (const int*)d_in[2] };
    const float* W[2] = { (const float*)d_in[3], (const float*)d_in[7] };
    const float* attS[2] = { (const float*)d_in[4], (const float*)d_in[8] };
    const float* attD[2] = { (const float*)d_in[5], (const float*)d_in[9] };
    const float* bias[2] = { (const float*)d_in[6], (const float*)d_in[10] };
    const float* fcW = (const float*)d_in[11];
    const float* fcb = (const float*)d_in[12];
    float* out = (float*)d_out;

    char* p = (char*)d_ws;
    size_t need = 0;
    auto carve = [&](size_t bytes) {
        char* r = p;
        size_t b = (bytes + 255) & ~(size_t)255;
        p += b;
        need += b;
        return r;
    };
    _Float16* h16 = (_Float16*)carve((size_t)2 * NN * HCH * 2);  // both layers
    _Float16* xc16 = (_Float16*)carve((size_t)NN * HCH * 2);
    _Float16* wt = (_Float16*)carve((size_t)2 * IN_DIM * HCH * 2);
    _Float16* fcw16 = (_Float16*)carve((size_t)2 * HCH * OUT_DIM * 2);
    float* a_s = (float*)carve((size_t)2 * NN * 8);              // [layer][node][head]
    float* a_d = (float*)carve((size_t)2 * NN * 8);
    int* gcursor = (int*)carve((size_t)NB * 4);
    int* bstore = (int*)carve((size_t)NB * CAP * 4);
    int* gstart = (int*)carve((size_t)NN * 4);
    int* gend = (int*)carve((size_t)NN * 4);
    if (need > ws_size) return;  // loud correctness failure instead of OOB crash

    const int gemm_blocks = (NN + 63) / 64;     // 1563
    const int agg_blocks = (NN + 15) / 16;      // 6250
    const int conv_total = 2 * IN_DIM * HCH + 2 * HCH * OUT_DIM;

    convw_kernel<<<(conv_total + 255) / 256, 256, 0, stream>>>(W[0], W[1], fcW, wt, fcw16);

    // one fused GEMM for both layers: reads x once
    gemm_mfma<<<gemm_blocks, 256, 0, stream>>>(x, wt, attS[0], attD[0], attS[1], attD[1],
                                               h16, a_s, a_d, NN);

    for (int layer = 0; layer < 2; ++layer) {
        hipMemsetAsync(gcursor, 0, (size_t)NB * 4, stream);
        bucket_kernel<<<256, 1024, 0, stream>>>(ei[layer], ei[layer] + EE, gcursor, bstore, EE);
        sort_kernel<<<NB, 256, 0, stream>>>(gcursor, bstore, gstart, gend, NN);
        agg_kernel<<<agg_blocks, 256, 0, stream>>>(
            h16 + (size_t)layer * NN * HCH,
            (const float2*)a_s + (size_t)layer * NN,
            (const float2*)a_d + (size_t)layer * NN,
            gstart, gend, bstore, bias[layer], xc16, NN);
        fc_mfma<<<gemm_blocks, 256, 0, stream>>>(xc16, fcw16 + (size_t)layer * HCH * OUT_DIM,
                                                 fcb, out, NN, layer);
    }
}

// Round 3
// 464.859 us; speedup vs baseline: 1.1429x; 1.0724x over previous
//
#include <hip/hip_runtime.h>
#include <hip/hip_fp16.h>
#include <math.h>

#define NN 100000
#define IN_DIM 256
#define HCH 128      // HEADS*HID
#define OUT_DIM 64
#define EE 1600000
#define NEG_SLOPE 0.2f

#define NB 1024      // dst buckets per layer
#define NPB 98       // nodes per bucket (1024*98 >= 100000)
#define CAP 2048     // bucket capacity (mean 1562, std ~40 -> 12 sigma margin)

typedef _Float16 half8v __attribute__((ext_vector_type(8)));
typedef _Float16 half4v __attribute__((ext_vector_type(4)));
typedef _Float16 half2v __attribute__((ext_vector_type(2)));
typedef __fp16 fp16x2 __attribute__((ext_vector_type(2)));   // clang builtin half2 type
typedef float float4v __attribute__((ext_vector_type(4)));
typedef unsigned int u32;

union H2U { u32 u; fp16x2 h; };

__device__ __forceinline__ float lrelu(float v) { return v > 0.f ? v : NEG_SLOPE * v; }

// ---- convert: wt[l][col][k] = W_l[k][col] fp16 ; fcw2[col][k] = fcW[k][col] (K=256)
__global__ void convw_kernel(const float* __restrict__ W0, const float* __restrict__ W1,
                             const float* __restrict__ fcW,
                             _Float16* __restrict__ wt, _Float16* __restrict__ fcw2)
{
    int i = blockIdx.x * 256 + threadIdx.x;
    if (i < 2 * IN_DIM * HCH) {
        int l = i >> 15, rem = i & 32767;
        int c = rem >> 8, k = rem & 255;
        const float* W = l ? W1 : W0;
        wt[i] = (_Float16)W[(size_t)k * HCH + c];
        return;
    }
    int j = i - 2 * IN_DIM * HCH;
    if (j < 256 * OUT_DIM) {
        int c = j >> 8, k = j & 255;   // fcw2[c*256 + k] = fcW[k][c]
        fcw2[j] = (_Float16)fcW[(size_t)k * OUT_DIM + c];
    }
}

// ---------------- fused GEMM (fp16 MFMA), BOTH layers in one pass ----------
// 64-row tiles, 1563 blocks; 4 waves as 2x2, wave tile 32x128 (2x8 frags)
__global__ __launch_bounds__(256, 3) void gemm_mfma(
    const float* __restrict__ x, const _Float16* __restrict__ wt,
    const float* __restrict__ attS0, const float* __restrict__ attD0,
    const float* __restrict__ attS1, const float* __restrict__ attD1,
    _Float16* __restrict__ h16, float* __restrict__ a_s, float* __restrict__ a_d, int n)
{
    __shared__ _Float16 smem[64 * 72 + 256 * 72];   // A[64][72] then B[256][72] = 46.1KB
    __shared__ float attv[4][128];                   // [layer*2+kind][col]
    _Float16 (*As)[72] = (_Float16(*)[72])smem;
    _Float16 (*Bs)[72] = (_Float16(*)[72])(smem + 64 * 72);
    const int tid = threadIdx.x;
    const int lane = tid & 63, wave = tid >> 6;
    const int wm = wave & 1, wn = wave >> 1;
    const int q = lane >> 4, r16 = lane & 15;
    const int row0 = blockIdx.x * 64;

    if (tid < 128) {
        attv[0][tid] = attS0[tid]; attv[1][tid] = attD0[tid];
        attv[2][tid] = attS1[tid]; attv[3][tid] = attD1[tid];
    }

    float4v acc[2][8];
#pragma unroll
    for (int i = 0; i < 2; ++i)
#pragma unroll
        for (int j = 0; j < 8; ++j) acc[i][j] = (float4v){0.f, 0.f, 0.f, 0.f};

    const int ar = tid >> 2, aq = tid & 3;   // A: row, k-quarter (16 floats)
    const bool rok = (row0 + ar) < n;
    for (int kt = 0; kt < IN_DIM; kt += 64) {
        const float* xp = x + (size_t)(row0 + ar) * IN_DIM + kt + aq * 16;
#pragma unroll
        for (int i = 0; i < 4; ++i) {
            float4 v = rok ? *(const float4*)(xp + i * 4) : make_float4(0.f, 0.f, 0.f, 0.f);
            half4v hv = { (_Float16)v.x, (_Float16)v.y, (_Float16)v.z, (_Float16)v.w };
            *(half4v*)&As[ar][aq * 16 + i * 4] = hv;
        }
        const _Float16* wp = wt + (size_t)tid * IN_DIM + kt;
#pragma unroll
        for (int i = 0; i < 8; ++i)
            *(half8v*)&Bs[tid][i * 8] = *(const half8v*)(wp + i * 8);
        __syncthreads();
#pragma unroll
        for (int s = 0; s < 2; ++s) {
            half8v af[2], bf[8];
#pragma unroll
            for (int t = 0; t < 2; ++t)
                af[t] = *(half8v*)&As[wm * 32 + t * 16 + r16][s * 32 + q * 8];
#pragma unroll
            for (int t = 0; t < 8; ++t)
                bf[t] = *(half8v*)&Bs[wn * 128 + t * 16 + r16][s * 32 + q * 8];
#pragma unroll
            for (int mt = 0; mt < 2; ++mt)
#pragma unroll
                for (int nt = 0; nt < 8; ++nt)
                    acc[mt][nt] = __builtin_amdgcn_mfma_f32_16x16x32_f16(
                        af[mt], bf[nt], acc[mt][nt], 0, 0, 0);
        }
        __syncthreads();
    }
    // epilogue: repack C to fp16 via LDS (C layout: row=q*4+reg, col=r16)
    _Float16 (*eb)[264] = (_Float16(*)[264])smem;
#pragma unroll
    for (int mt = 0; mt < 2; ++mt) {
        const int er = wm * 32 + mt * 16 + q * 4;
#pragma unroll
        for (int reg = 0; reg < 4; ++reg)
#pragma unroll
            for (int nt = 0; nt < 8; ++nt)
                eb[er + reg][wn * 128 + nt * 16 + r16] = (_Float16)acc[mt][nt][reg];
    }
    __syncthreads();
    const int r = tid >> 2, qq = tid & 3;    // qq: 64-col quarter -> (layer, head)
    const int grow = row0 + r;
    if (grow < n) {
        const int l2 = qq >> 1;
        const int hh = qq & 1;
        const float* avS = &attv[l2 * 2 + 0][hh * 64];
        const float* avD = &attv[l2 * 2 + 1][hh * 64];
        _Float16* hout = h16 + (size_t)l2 * NN * HCH + (size_t)grow * HCH + hh * 64;
        float ds = 0.f, dd = 0.f;
#pragma unroll
        for (int i = 0; i < 8; ++i) {
            half8v v = *(half8v*)&eb[r][qq * 64 + i * 8];
            *(half8v*)(hout + i * 8) = v;
#pragma unroll
            for (int j = 0; j < 8; ++j) {
                float f = (float)v[j];
                ds = fmaf(f, avS[i * 8 + j], ds);
                dd = fmaf(f, avD[i * 8 + j], dd);
            }
        }
        a_s[(size_t)l2 * 2 * NN + 2 * grow + hh] = ds;
        a_d[(size_t)l2 * 2 * NN + 2 * grow + hh] = dd;
    }
}

// ---------------- bucket edges by dst region, BOTH layers (grid.y=2) --------
__global__ __launch_bounds__(1024) void bucket_kernel(const int* __restrict__ ei0,
                                                      const int* __restrict__ ei1,
                                                      int* __restrict__ gcursor,
                                                      int* __restrict__ bstore, int e)
{
    __shared__ int hist[NB];
    __shared__ int base[NB];
    const int lay = blockIdx.y;
    const int* src = lay ? ei1 : ei0;
    const int* dst = src + e;
    int* gcur = gcursor + lay * NB;
    int* bst = bstore + (size_t)lay * NB * CAP;

    const int tid = threadIdx.x;
    const int per = (e + gridDim.x - 1) / gridDim.x;
    const int e0 = blockIdx.x * per;
    const int e1 = min(e, e0 + per);
    for (int i = tid; i < NB; i += 1024) hist[i] = 0;
    __syncthreads();
    for (int i = e0 + tid; i < e1; i += 1024)
        atomicAdd(&hist[dst[i] / NPB], 1);
    __syncthreads();
    for (int b = tid; b < NB; b += 1024) {
        int c = hist[b];
        base[b] = c ? atomicAdd(&gcur[b], c) : 0;
        hist[b] = 0;
    }
    __syncthreads();
    for (int i = e0 + tid; i < e1; i += 1024) {
        int d = dst[i];
        int s = src[i];
        int b = d / NPB;
        int pos = base[b] + atomicAdd(&hist[b], 1);
        if (pos >= 0 && pos < CAP) bst[b * CAP + pos] = (s << 7) | (d - b * NPB);
    }
}

// ---------------- per-bucket LDS counting sort, BOTH layers (grid.y=2) ------
__global__ __launch_bounds__(256) void sort_kernel(
    const int* __restrict__ gcursor, int* __restrict__ bstore,
    int* __restrict__ gstart, int* __restrict__ gend, int n)
{
    __shared__ int raw[CAP];
    __shared__ int sorted[CAP];
    __shared__ int curs[128];
    __shared__ int scanbuf[128];
    const int lay = blockIdx.y;
    const int* gcur = gcursor + lay * NB;
    int* bst = bstore + (size_t)lay * NB * CAP;
    int* gs = gstart + (size_t)lay * NN;
    int* ge = gend + (size_t)lay * NN;

    const int tid = threadIdx.x;
    const int b = blockIdx.x;
    const int node0 = b * NPB;
    const int nnode = min(NPB, n - node0);
    if (nnode <= 0) return;
    int cnt = gcur[b];
    cnt = cnt < 0 ? 0 : (cnt > CAP ? CAP : cnt);

    for (int i = tid; i < cnt; i += 256) raw[i] = bst[b * CAP + i];
    if (tid < 128) curs[tid] = 0;
    __syncthreads();
    for (int i = tid; i < cnt; i += 256) atomicAdd(&curs[raw[i] & 127], 1);
    __syncthreads();
    if (tid < 128) scanbuf[tid] = curs[tid];
    __syncthreads();
    for (int off = 1; off < 128; off <<= 1) {
        int v = 0;
        if (tid < 128) { v = scanbuf[tid]; if (tid >= off) v += scanbuf[tid - off]; }
        __syncthreads();
        if (tid < 128) scanbuf[tid] = v;
        __syncthreads();
    }
    if (tid < 128) {
        int ex = tid ? scanbuf[tid - 1] : 0;
        curs[tid] = ex;
        if (tid < nnode) {
            gs[node0 + tid] = b * CAP + ex;
            ge[node0 + tid] = b * CAP + scanbuf[tid];
        }
    }
    __syncthreads();
    for (int i = tid; i < cnt; i += 256) {
        int item = raw[i];
        int pos = atomicAdd(&curs[item & 127], 1);
        if (pos >= 0 && pos < CAP) sorted[pos] = item >> 7;
    }
    __syncthreads();
    for (int i = tid; i < cnt; i += 256) bst[b * CAP + i] = sorted[i];
}

// ---------------- per-node softmax aggregation, BOTH layers (grid.y=2) ------
// Each wave handles 4 nodes. 8 edges per wave-iteration: lane = w2*16 + cl,
// lane covers 2 edges (fdot2 pairs) x 8 cols. Staged slot record = 8B
// {src, half2(p0,p1)}; one ds_read_b128 fetches 2 slots. Denominator folds
// into the same dot2 stream (dotted with (1,1)) and shares the w2-reduce.
__global__ __launch_bounds__(256) void agg_kernel(
    const _Float16* __restrict__ h16, const float2* __restrict__ a_s,
    const float2* __restrict__ a_d, const int* __restrict__ gstart,
    const int* __restrict__ gend, const int* __restrict__ bstore,
    const float* __restrict__ bias0, const float* __restrict__ bias1,
    _Float16* __restrict__ xc16, int n)
{
    __shared__ __align__(16) uint2 sh[4][64];   // [wave][slot]: {src, half2 p}
    const int lay = blockIdx.y;
    const _Float16* hL = h16 + (size_t)lay * NN * HCH;
    const float2* asL = a_s + (size_t)lay * NN;
    const float2* adL = a_d + (size_t)lay * NN;
    const int* gsL = gstart + (size_t)lay * NN;
    const int* geL = gend + (size_t)lay * NN;
    const int* ssort = bstore + (size_t)lay * NB * CAP;
    const float* bias = lay ? bias1 : bias0;

    const int wid = threadIdx.x >> 6, lane = threadIdx.x & 63;
    const int wbase = (blockIdx.x * 4 + wid) * 4;
    const int cl = lane & 15;         // column group: cols 8*cl .. 8*cl+7
    const int w2 = lane >> 4;         // edge-pair sub-slot 0..3
    const int hh = cl >> 3;           // head for these columns
    const u32 psel = hh ? 0x07060302u : 0x05040100u;
    const fp16x2 one2 = { (__fp16)1.f, (__fp16)1.f };

    float bv[8];
#pragma unroll
    for (int j = 0; j < 8; ++j) bv[j] = bias[cl * 8 + j];

    for (int ni = 0; ni < 4; ++ni) {
        const int node = wbase + ni;
        const bool valid = node < n;
        const int nn = valid ? node : 0;
        int start = gsL[nn], end = geL[nn];
        start = start < 0 ? 0 : (start > NB * CAP ? NB * CAP : start);
        end = end < start ? start : (end > NB * CAP ? NB * CAP : end);
        const float2 ad = adL[nn];
        const float2 asn = asL[nn];

        float acc[8] = {0.f, 0.f, 0.f, 0.f, 0.f, 0.f, 0.f, 0.f};
        float den = 0.f;

        for (int base = start; base < end; base += 64) {
            const int j = base + lane;
            const int cnt = min(64, end - base);
            float p0 = 0.f, p1 = 0.f;
            int s = 0;
            if (j < end) {
                s = ssort[j];
                if ((unsigned)s >= (unsigned)n) s = 0;   // poison guard
                float2 a = asL[s];
                p0 = __expf(lrelu(a.x + ad.x));
                p1 = __expf(lrelu(a.y + ad.y));
            }
            H2U pk; pk.h = __builtin_amdgcn_cvt_pkrtz(p0, p1);
            sh[wid][lane] = make_uint2((u32)s, pk.u);
            __builtin_amdgcn_wave_barrier();
            const int cnt8 = (cnt + 7) & ~7;
            for (int t = 0; t < cnt8; t += 8) {
                const uint4 rec = *(const uint4*)&sh[wid][t + 2 * w2];
                H2U pph; pph.u = __builtin_amdgcn_perm(rec.w, rec.y, psel);
                const half8v hv0 = *(const half8v*)(hL + ((rec.x << 7) | (u32)(cl << 3)));
                const half8v hv1 = *(const half8v*)(hL + ((rec.z << 7) | (u32)(cl << 3)));
                const u32* ap = (const u32*)&hv0;
                const u32* bp = (const u32*)&hv1;
#pragma unroll
                for (int d2 = 0; d2 < 4; ++d2) {
                    H2U pe, po;
                    pe.u = __builtin_amdgcn_perm(bp[d2], ap[d2], 0x05040100u);
                    po.u = __builtin_amdgcn_perm(bp[d2], ap[d2], 0x07060302u);
                    acc[2 * d2]     = __builtin_amdgcn_fdot2(pe.h, pph.h, acc[2 * d2], false);
                    acc[2 * d2 + 1] = __builtin_amdgcn_fdot2(po.h, pph.h, acc[2 * d2 + 1], false);
                }
                den = __builtin_amdgcn_fdot2(pph.h, one2, den, false);
            }
            __builtin_amdgcn_wave_barrier();
        }
        // self loop (w2==0 group only, so it is counted once after the reduce)
        const float ps0 = __expf(lrelu(asn.x + ad.x));
        const float ps1 = __expf(lrelu(asn.y + ad.y));
        if (w2 == 0) {
            const half8v hv = *(const half8v*)(hL + (((u32)nn << 7) | (u32)(cl << 3)));
            const float pl = hh ? ps1 : ps0;
#pragma unroll
            for (int j2 = 0; j2 < 8; ++j2)
                acc[j2] = fmaf(pl, (float)hv[j2], acc[j2]);
            den += pl;
        }
        // combine the 4 edge-pair sub-slots (numerators + denominator together)
#pragma unroll
        for (int j2 = 0; j2 < 8; ++j2) {
            acc[j2] += __shfl_xor(acc[j2], 16, 64);
            acc[j2] += __shfl_xor(acc[j2], 32, 64);
        }
        den += __shfl_xor(den, 16, 64);
        den += __shfl_xor(den, 32, 64);
        if (valid && lane < 16) {
            const float inv = 1.f / den;
            half8v o;
#pragma unroll
            for (int j2 = 0; j2 < 8; ++j2)
                o[j2] = (_Float16)fmaxf(acc[j2] * inv + bv[j2], 0.f);
            *(half8v*)(xc16 + (size_t)node * 256 + lay * HCH + cl * 8) = o;
        }
    }
}

// ---------------- FC via MFMA, K=256 concat: out = [xc0|xc1] @ fcW + fcb ----
__global__ __launch_bounds__(256) void fc_mfma(const _Float16* __restrict__ xc16,
                                               const _Float16* __restrict__ fw2,
                                               const float* __restrict__ fcb,
                                               float* __restrict__ out, int n)
{
    __shared__ _Float16 axs[64][264];
    const int tid = threadIdx.x;
    const int lane = tid & 63, wave = tid >> 6;
    const int q = lane >> 4, r16 = lane & 15;
    const int row0 = blockIdx.x * 64;

    // stage A: 64 rows x 256 k (8 half8 loads/thread, coalesced)
#pragma unroll
    for (int i = 0; i < 8; ++i) {
        const int idx = i * 256 + tid;
        const int row = idx >> 5;
        const int kg = (idx & 31) * 8;
        half8v v = { 0, 0, 0, 0, 0, 0, 0, 0 };
        if (row0 + row < n)
            v = *(const half8v*)(xc16 + (size_t)(row0 + row) * 256 + kg);
        *(half8v*)&axs[row][kg] = v;
    }
    __syncthreads();

    float4v acc[4];
#pragma unroll
    for (int i = 0; i < 4; ++i) acc[i] = (float4v){0.f, 0.f, 0.f, 0.f};
#pragma unroll
    for (int s = 0; s < 8; ++s) {
        const half8v af = *(half8v*)&axs[wave * 16 + r16][s * 32 + q * 8];
#pragma unroll
        for (int nt = 0; nt < 4; ++nt) {
            const half8v bf =
                *(const half8v*)(fw2 + (size_t)(nt * 16 + r16) * 256 + s * 32 + q * 8);
            acc[nt] = __builtin_amdgcn_mfma_f32_16x16x32_f16(af, bf, acc[nt], 0, 0, 0);
        }
    }
#pragma unroll
    for (int nt = 0; nt < 4; ++nt) {
        const int col = nt * 16 + r16;
#pragma unroll
        for (int reg = 0; reg < 4; ++reg) {
            const int row = row0 + wave * 16 + q * 4 + reg;
            if (row < n)
                out[(size_t)row * OUT_DIM + col] = acc[nt][reg] + fcb[col];
        }
    }
}

// ---------------- launch ----------------
extern "C" void kernel_launch(void* const* d_in, const int* in_sizes, int n_in,
                              void* d_out, int out_size, void* d_ws, size_t ws_size,
                              hipStream_t stream)
{
    const float* x = (const float*)d_in[0];
    const int* ei[2] = { (const int*)d_in[1], (const int*)d_in[2] };
    const float* W[2] = { (const float*)d_in[3], (const float*)d_in[7] };
    const float* attS[2] = { (const float*)d_in[4], (const float*)d_in[8] };
    const float* attD[2] = { (const float*)d_in[5], (const float*)d_in[9] };
    const float* bias[2] = { (const float*)d_in[6], (const float*)d_in[10] };
    const float* fcW = (const float*)d_in[11];
    const float* fcb = (const float*)d_in[12];
    float* out = (float*)d_out;

    char* p = (char*)d_ws;
    size_t need = 0;
    auto carve = [&](size_t bytes) {
        char* r = p;
        size_t b = (bytes + 255) & ~(size_t)255;
        p += b;
        need += b;
        return r;
    };
    _Float16* h16 = (_Float16*)carve((size_t)2 * NN * HCH * 2);    // both layers
    _Float16* xc16 = (_Float16*)carve((size_t)NN * 256 * 2);       // concat rows
    _Float16* wt = (_Float16*)carve((size_t)2 * IN_DIM * HCH * 2);
    _Float16* fcw2 = (_Float16*)carve((size_t)256 * OUT_DIM * 2);
    float* a_s = (float*)carve((size_t)2 * NN * 8);                // [layer][node][head]
    float* a_d = (float*)carve((size_t)2 * NN * 8);
    int* gcursor = (int*)carve((size_t)2 * NB * 4);
    int* bstore = (int*)carve((size_t)2 * NB * CAP * 4);
    int* gstart = (int*)carve((size_t)2 * NN * 4);
    int* gend = (int*)carve((size_t)2 * NN * 4);
    if (need > ws_size) return;  // loud correctness failure instead of OOB crash

    const int gemm_blocks = (NN + 63) / 64;     // 1563
    const int agg_blocks = (NN + 15) / 16;      // 6250
    const int conv_total = 2 * IN_DIM * HCH + 256 * OUT_DIM;

    convw_kernel<<<(conv_total + 255) / 256, 256, 0, stream>>>(W[0], W[1], fcW, wt, fcw2);

    gemm_mfma<<<gemm_blocks, 256, 0, stream>>>(x, wt, attS[0], attD[0], attS[1], attD[1],
                                               h16, a_s, a_d, NN);

    (void)hipMemsetAsync(gcursor, 0, (size_t)2 * NB * 4, stream);
    bucket_kernel<<<dim3(256, 2), 1024, 0, stream>>>(ei[0], ei[1], gcursor, bstore, EE);
    sort_kernel<<<dim3(NB, 2), 256, 0, stream>>>(gcursor, bstore, gstart, gend, NN);
    agg_kernel<<<dim3(agg_blocks, 2), 256, 0, stream>>>(
        h16, (const float2*)a_s, (const float2*)a_d,
        gstart, gend, bstore, bias[0], bias[1], xc16, NN);
    fc_mfma<<<gemm_blocks, 256, 0, stream>>>(xc16, fcw2, fcb, out, NN);
}